// Round 3
// baseline (775.547 us; speedup 1.0000x reference)
//
#include <hip/hip_runtime.h>
#include <math.h>

#define NH   6     // heads
#define NTOK 64    // tokens per 8x8 window
#define HD   24    // head dim
#define NWX  32    // windows per axis (256/8)

// 16*sigmoid(CPB-MLP bias), layout [h][n][m]
__device__ float g_bias[NH * NTOK * NTOK];

// ---------------- DPP helpers (VALU-pipe cross-lane reduce over 8 lanes) ----
template <int CTRL>
__device__ __forceinline__ float dppmov(float x) {
  return __int_as_float(__builtin_amdgcn_update_dpp(
      0, __float_as_int(x), CTRL, 0xF, 0xF, true));
}
// full sum across each aligned 8-lane group: xor1, xor2, half-mirror
__device__ __forceinline__ float red8(float x) {
  x += dppmov<0xB1>(x);   // quad_perm [1,0,3,2]  : lane ^ 1
  x += dppmov<0x4E>(x);   // quad_perm [2,3,0,1]  : lane ^ 2
  x += dppmov<0x141>(x);  // row_half_mirror      : lane ^ 7 in 8-group
  return x;
}

// ---------------- CPB-MLP bias precompute: grid(6), block(256) --------------
// table(225,2) -> relu(t@w1+b1)@w2 -> gather by rel-pos index -> 16*sigmoid
__global__ void cpb_bias_kernel(const float* __restrict__ w1,
                                const float* __restrict__ b1,
                                const float* __restrict__ w2) {
  __shared__ float bt[225];
  const int t = threadIdx.x;
  const int h = blockIdx.x;
  if (t < 225) {
    const int i = t / 15, j = t % 15;
    const float xy = (float)(i - 7) * (8.0f / 7.0f);
    const float xx = (float)(j - 7) * (8.0f / 7.0f);
    // sign(x)*log2(|x|+1)/log2(8); x==0 gives 0 either way
    const float dy = copysignf(log2f(fabsf(xy) + 1.0f) * (1.0f / 3.0f), xy);
    const float dx = copysignf(log2f(fabsf(xx) + 1.0f) * (1.0f / 3.0f), xx);
    float acc = 0.0f;
    for (int u = 0; u < 512; ++u) {
      float hv = fmaf(dy, w1[u], fmaf(dx, w1[512 + u], b1[u]));
      hv = fmaxf(hv, 0.0f);
      acc = fmaf(hv, w2[u * NH + h], acc);
    }
    bt[t] = acc;
  }
  __syncthreads();
  for (int e = t; e < NTOK * NTOK; e += 256) {
    const int n = e >> 6, m = e & 63;
    const int dr = (n >> 3) - (m >> 3) + 7;
    const int dc = (n & 7) - (m & 7) + 7;
    const float v = bt[dr * 15 + dc];
    g_bias[(h << 12) + e] = 16.0f / (1.0f + expf(-v));
  }
}

// ---------------- main fused window-attention kernel ------------------------
// grid = (NH, 1024 windows, B); block = 128 (2 waves)
// thread tile: 4 rows x 8 cols of the 64x64 attn matrix
// lane = nr*8 + jm ; rows n = wave*32 + nr*4 + rr ; cols m = jm + 8*mi
__global__ __launch_bounds__(128, 2)
void win_attn_kernel(const float* __restrict__ qkv,
                     const float* __restrict__ logit_scale,
                     float* __restrict__ out) {
  __shared__ __align__(16) float sk[NTOK * HD];  // K rows (6 KB)
  __shared__ __align__(16) float sv[NTOK * HD];  // V rows (6 KB)
  __shared__ float sik[NTOK];                    // 1/||k|| per row

  const int t    = threadIdx.x;
  const int wv   = t >> 6;
  const int lane = t & 63;
  const int nr   = lane >> 3;
  const int jm   = lane & 7;
  const int h    = blockIdx.x;
  const int wh   = blockIdx.y >> 5;
  const int ww   = blockIdx.y & 31;
  const int b    = blockIdx.z;

  // ---- Q rows -> registers FIRST (issue-early: HBM latency hides under
  //      the K/V staging loop + barrier below) ----
  float q[4][HD];
  int   rowN[4], idn[4];
#pragma unroll
  for (int rr = 0; rr < 4; ++rr) {
    const int n = wv * 32 + nr * 4 + rr;
    rowN[rr] = n;
    const int r = n >> 3, c = n & 7;
    const int hg = (wh * 8 + r + 4) & 255;
    const int wg = (ww * 8 + c + 4) & 255;
    const float* qp = qkv + (size_t)((b * 256 + hg) * 256 + wg) * 432 + 24 * h;
#pragma unroll
    for (int i = 0; i < 6; ++i) {
      const float4 v4 = *(const float4*)(qp + 4 * i);
      q[rr][4 * i + 0] = v4.x; q[rr][4 * i + 1] = v4.y;
      q[rr][4 * i + 2] = v4.z; q[rr][4 * i + 3] = v4.w;
    }
    // shifted-window region id (nonzero only in last window row/col),
    // in ROLLED coordinates, matching _calc_mask's slices
    idn[rr] = ((wh == 31) ? (r < 4 ? 1 : 2) : 0) * 3
            + ((ww == 31) ? (c < 4 ? 1 : 2) : 0);
  }

  // ---- stage K,V into LDS (shifted-window gather; g = (y+4) & 255) ----
#pragma unroll
  for (int it = 0; it < 6; ++it) {
    const int f      = t + 128 * it;       // 0..767 float4 chunks (k then v)
    const int tensor = (f >= 384) ? 1 : 0;
    const int rem    = f - 384 * tensor;
    const int row    = rem / 6;
    const int ch     = rem - row * 6;
    const int r = row >> 3, c = row & 7;
    const int hg = (wh * 8 + r + 4) & 255;
    const int wg = (ww * 8 + c + 4) & 255;
    const size_t goff = (size_t)((b * 256 + hg) * 256 + wg) * 432
                      + 144 + 144 * tensor + 24 * h + 4 * ch;
    const float4 v4 = *(const float4*)(qkv + goff);
    float* dst = (tensor ? sv : sk) + row * HD + 4 * ch;
    *(float4*)dst = v4;
  }

  // ---- bias + mask preload into the P register block (issue-early: these
  //      32 L2-ish loads drain under q-normalize + barrier + QK^T FMAs,
  //      instead of stalling the inner loop) ----
  float P[4][8];
  {
    const int idwm = (ww == 31) ? (jm < 4 ? 1 : 2) : 0;  // col-region, c2 = jm
#pragma unroll
    for (int mi = 0; mi < 8; ++mi) {
      const int idm = ((wh == 31) ? (mi < 4 ? 1 : 2) : 0) * 3 + idwm;
      const float* bp = g_bias + (h << 12) + jm + 8 * mi;
#pragma unroll
      for (int rr = 0; rr < 4; ++rr) {
        P[rr][mi] = bp[rowN[rr] << 6] + ((idm == idn[rr]) ? 0.0f : -100.0f);
      }
    }
  }
  __syncthreads();

  // ---- 1/||k_m|| (wave 0 only; wave-uniform branch, no divergence) ----
  if (t < 64) {
    const float4* kp = (const float4*)(sk + t * HD);
    float ss = 0.0f;
#pragma unroll
    for (int i = 0; i < 6; ++i) {
      const float4 k4 = kp[i];
      ss = fmaf(k4.x, k4.x, fmaf(k4.y, k4.y, fmaf(k4.z, k4.z, fmaf(k4.w, k4.w, ss))));
    }
    sik[t] = 1.0f / fmaxf(sqrtf(ss), 1e-12f);
  }

  // ---- normalize q by logit_scale/||q|| (q already in registers) ----
  const float scale = expf(fminf(logit_scale[h], 4.6051701860f));  // ln(100)
#pragma unroll
  for (int rr = 0; rr < 4; ++rr) {
    float ss = 0.0f;
#pragma unroll
    for (int d = 0; d < HD; ++d) ss = fmaf(q[rr][d], q[rr][d], ss);
    const float sc = scale / fmaxf(sqrtf(ss), 1e-12f);
#pragma unroll
    for (int d = 0; d < HD; ++d) q[rr][d] *= sc;
  }
  __syncthreads();  // sik visible (k/v staged earlier)

  // ---- QK^T * scale + (preloaded bias+mask) -> exp, running row sums ----
  // no max-subtraction needed: s <= 10*1 + 16 = 26, exp(26) ~ 2e11 (f32-safe)
  float sum[4] = {0.f, 0.f, 0.f, 0.f};
#pragma unroll
  for (int mi = 0; mi < 8; ++mi) {
    const int m = jm + 8 * mi;                          // r2 = mi
    float kv[HD];
    {
      const float4* kp = (const float4*)(sk + m * HD);
#pragma unroll
      for (int i = 0; i < 6; ++i) {
        const float4 v4 = kp[i];
        kv[4 * i] = v4.x; kv[4 * i + 1] = v4.y; kv[4 * i + 2] = v4.z; kv[4 * i + 3] = v4.w;
      }
    }
    const float ik = sik[m];
#pragma unroll
    for (int rr = 0; rr < 4; ++rr) {
      float s = 0.0f;
#pragma unroll
      for (int d = 0; d < HD; ++d) s = fmaf(q[rr][d], kv[d], s);
      const float e = __expf(fmaf(s, ik, P[rr][mi]));
      P[rr][mi] = e;
      sum[rr] += e;
    }
  }

  // ---- softmax denominators (8-lane DPP reduce) ----
  float rs[4];
#pragma unroll
  for (int rr = 0; rr < 4; ++rr) rs[rr] = 1.0f / red8(sum[rr]);

  // ---- PV ----
  float acc[4][HD];
#pragma unroll
  for (int rr = 0; rr < 4; ++rr)
#pragma unroll
    for (int d = 0; d < HD; ++d) acc[rr][d] = 0.0f;

#pragma unroll
  for (int mi = 0; mi < 8; ++mi) {
    const int m = jm + 8 * mi;
    float vv[HD];
    const float4* vp = (const float4*)(sv + m * HD);
#pragma unroll
    for (int i = 0; i < 6; ++i) {
      const float4 v4 = vp[i];
      vv[4 * i] = v4.x; vv[4 * i + 1] = v4.y; vv[4 * i + 2] = v4.z; vv[4 * i + 3] = v4.w;
    }
#pragma unroll
    for (int rr = 0; rr < 4; ++rr) {
      const float p = P[rr][mi];
#pragma unroll
      for (int d = 0; d < HD; ++d) acc[rr][d] = fmaf(p, vv[d], acc[rr][d]);
    }
  }

  // ---- scale + cross-lane reduce (all 8 lanes end with full sums) ----
#pragma unroll
  for (int rr = 0; rr < 4; ++rr)
#pragma unroll
    for (int d = 0; d < HD; ++d) acc[rr][d] = red8(acc[rr][d] * rs[rr]);

  // ---- store: lane jm -> (row jm&3, 12-float half jm>>2); cndmask select
  // (no runtime register-array indexing -> no scratch, rule #20) ----
  float o[12];
  const int s0 = jm & 1, s1 = jm & 2, s2 = jm & 4;
#pragma unroll
  for (int k = 0; k < 12; ++k) {
    const float lo = s1 ? (s0 ? acc[3][k] : acc[2][k])
                        : (s0 ? acc[1][k] : acc[0][k]);
    const float hi = s1 ? (s0 ? acc[3][12 + k] : acc[2][12 + k])
                        : (s0 ? acc[1][12 + k] : acc[0][12 + k]);
    o[k] = s2 ? hi : lo;
  }
  {
    const int n = wv * 32 + nr * 4 + (jm & 3);
    const int r = n >> 3, c = n & 7;
    const int hg = (wh * 8 + r + 4) & 255;
    const int wg = (ww * 8 + c + 4) & 255;
    float* op = out + (size_t)((b * 256 + hg) * 256 + wg) * 144
              + 24 * h + 12 * ((jm >> 2) & 1);
    *(float4*)(op + 0) = make_float4(o[0], o[1], o[2],  o[3]);
    *(float4*)(op + 4) = make_float4(o[4], o[5], o[6],  o[7]);
    *(float4*)(op + 8) = make_float4(o[8], o[9], o[10], o[11]);
  }
}

// ---------------- launcher --------------------------------------------------
extern "C" void kernel_launch(void* const* d_in, const int* in_sizes, int n_in,
                              void* d_out, int out_size, void* d_ws, size_t ws_size,
                              hipStream_t stream) {
  (void)n_in; (void)out_size; (void)d_ws; (void)ws_size;
  const float* qkv = (const float*)d_in[0];
  const float* ls  = (const float*)d_in[1];
  const float* w1  = (const float*)d_in[2];
  const float* b1  = (const float*)d_in[3];
  const float* w2  = (const float*)d_in[4];
  // d_in[5], d_in[6] are H, W (256, 256) — compile-time constants here
  float* outp = (float*)d_out;
  const int B = in_sizes[0] / (256 * 256 * 432);

  hipLaunchKernelGGL(cpb_bias_kernel, dim3(NH), dim3(256), 0, stream,
                     w1, b1, w2);
  hipLaunchKernelGGL(win_attn_kernel, dim3(NH, NWX * NWX, B), dim3(128), 0,
                     stream, qkv, ls, outp);
}

// Round 4
// 723.329 us; speedup vs baseline: 1.0722x; 1.0722x over previous
//
#include <hip/hip_runtime.h>
#include <math.h>

#define NH   6     // heads
#define NTOK 64    // tokens per 8x8 window
#define HD   24    // head dim
#define NWX  32    // windows per axis (256/8)

// CPB-MLP head outputs per table entry, layout [h][entry] (225 entries)
__device__ float g_bt[NH * 225];
// 16*sigmoid(CPB-MLP bias), layout [h][n][m]
__device__ float g_bias[NH * NTOK * NTOK];

// ---------------- DPP helpers (VALU-pipe cross-lane reduce over 8 lanes) ----
template <int CTRL>
__device__ __forceinline__ float dppmov(float x) {
  return __int_as_float(__builtin_amdgcn_update_dpp(
      0, __float_as_int(x), CTRL, 0xF, 0xF, true));
}
// full sum across each aligned 8-lane group: xor1, xor2, half-mirror
__device__ __forceinline__ float red8(float x) {
  x += dppmov<0xB1>(x);   // quad_perm [1,0,3,2]  : lane ^ 1
  x += dppmov<0x4E>(x);   // quad_perm [2,3,0,1]  : lane ^ 2
  x += dppmov<0x141>(x);  // row_half_mirror      : lane ^ 7 in 8-group
  return x;
}

// ---------------- CPB-MLP stage 1: grid(225), block(512) --------------------
// One block per table entry e; thread u owns hidden unit u (coalesced loads),
// 6 head partials reduced wave-wise (shfl_xor) then cross-wave via LDS.
__global__ void cpb_mlp_kernel(const float* __restrict__ w1,
                               const float* __restrict__ b1,
                               const float* __restrict__ w2) {
  const int e = blockIdx.x;        // 0..224
  const int u = threadIdx.x;       // 0..511
  const int i = e / 15, j = e % 15;
  const float xy = (float)(i - 7) * (8.0f / 7.0f);
  const float xx = (float)(j - 7) * (8.0f / 7.0f);
  // sign(x)*log2(|x|+1)/log2(8); x==0 gives 0 either way
  const float dy = copysignf(log2f(fabsf(xy) + 1.0f) * (1.0f / 3.0f), xy);
  const float dx = copysignf(log2f(fabsf(xx) + 1.0f) * (1.0f / 3.0f), xx);

  const float hv = fmaxf(fmaf(dy, w1[u], fmaf(dx, w1[512 + u], b1[u])), 0.0f);
  float p[NH];
#pragma unroll
  for (int h = 0; h < NH; ++h) p[h] = hv * w2[u * NH + h];

  // full-wave (64) butterfly reduce for each head partial
#pragma unroll
  for (int h = 0; h < NH; ++h)
#pragma unroll
    for (int off = 32; off >= 1; off >>= 1) p[h] += __shfl_xor(p[h], off);

  __shared__ float sred[8][NH];
  const int wave = u >> 6, lane = u & 63;
  if (lane == 0) {
#pragma unroll
    for (int h = 0; h < NH; ++h) sred[wave][h] = p[h];
  }
  __syncthreads();
  if (u < NH) {
    float a = 0.0f;
#pragma unroll
    for (int w = 0; w < 8; ++w) a += sred[w][u];
    g_bt[u * 225 + e] = a;
  }
}

// ---------------- CPB-MLP stage 2: gather + 16*sigmoid: grid(96), block(256)
__global__ void cpb_gather_kernel() {
  const int g = blockIdx.x * 256 + threadIdx.x;   // 0..24575
  const int h = g >> 12;
  const int e = g & 4095;
  const int n = e >> 6, m = e & 63;
  const int dr = (n >> 3) - (m >> 3) + 7;
  const int dc = (n & 7) - (m & 7) + 7;
  const float v = g_bt[h * 225 + dr * 15 + dc];
  g_bias[g] = 16.0f / (1.0f + expf(-v));
}

// ---------------- main fused window-attention kernel ------------------------
// grid = (NH, 1024 windows, B); block = 128 (2 waves)
// thread tile: 4 rows x 8 cols of the 64x64 attn matrix
// lane = nr*8 + jm ; rows n = wave*32 + nr*4 + rr ; cols m = jm + 8*mi
__global__ __launch_bounds__(128, 2)
void win_attn_kernel(const float* __restrict__ qkv,
                     const float* __restrict__ logit_scale,
                     float* __restrict__ out) {
  __shared__ __align__(16) float sk[NTOK * HD];  // K rows (6 KB)
  __shared__ __align__(16) float sv[NTOK * HD];  // V rows (6 KB)
  __shared__ float sik[NTOK];                    // 1/||k|| per row

  const int t    = threadIdx.x;
  const int wv   = t >> 6;
  const int lane = t & 63;
  const int nr   = lane >> 3;
  const int jm   = lane & 7;
  const int h    = blockIdx.x;
  const int wh   = blockIdx.y >> 5;
  const int ww   = blockIdx.y & 31;
  const int b    = blockIdx.z;

  // ---- Q rows -> registers FIRST (issue-early: HBM latency hides under
  //      the K/V staging loop + barrier below) ----
  float q[4][HD];
  int   rowN[4], idn[4];
#pragma unroll
  for (int rr = 0; rr < 4; ++rr) {
    const int n = wv * 32 + nr * 4 + rr;
    rowN[rr] = n;
    const int r = n >> 3, c = n & 7;
    const int hg = (wh * 8 + r + 4) & 255;
    const int wg = (ww * 8 + c + 4) & 255;
    const float* qp = qkv + (size_t)((b * 256 + hg) * 256 + wg) * 432 + 24 * h;
#pragma unroll
    for (int i = 0; i < 6; ++i) {
      const float4 v4 = *(const float4*)(qp + 4 * i);
      q[rr][4 * i + 0] = v4.x; q[rr][4 * i + 1] = v4.y;
      q[rr][4 * i + 2] = v4.z; q[rr][4 * i + 3] = v4.w;
    }
    // shifted-window region id (mask built on UNROLLED img coords; window
    // (wh,ww) local (r,c) -> img row wh*8+r), matching _calc_mask's slices
    idn[rr] = ((wh == 31) ? (r < 4 ? 1 : 2) : 0) * 3
            + ((ww == 31) ? (c < 4 ? 1 : 2) : 0);
  }

  // ---- stage K,V into LDS (shifted-window gather; g = (y+4) & 255) ----
#pragma unroll
  for (int it = 0; it < 6; ++it) {
    const int f      = t + 128 * it;       // 0..767 float4 chunks (k then v)
    const int tensor = (f >= 384) ? 1 : 0;
    const int rem    = f - 384 * tensor;
    const int row    = rem / 6;
    const int ch     = rem - row * 6;
    const int r = row >> 3, c = row & 7;
    const int hg = (wh * 8 + r + 4) & 255;
    const int wg = (ww * 8 + c + 4) & 255;
    const size_t goff = (size_t)((b * 256 + hg) * 256 + wg) * 432
                      + 144 + 144 * tensor + 24 * h + 4 * ch;
    const float4 v4 = *(const float4*)(qkv + goff);
    float* dst = (tensor ? sv : sk) + row * HD + 4 * ch;
    *(float4*)dst = v4;
  }

  // ---- bias + mask preload into the P register block (issue-early: these
  //      32 L2-ish loads drain under q-normalize + barrier + QK^T FMAs) ----
  float P[4][8];
  {
    const int idwm = (ww == 31) ? (jm < 4 ? 1 : 2) : 0;  // col-region, c2 = jm
#pragma unroll
    for (int mi = 0; mi < 8; ++mi) {
      const int idm = ((wh == 31) ? (mi < 4 ? 1 : 2) : 0) * 3 + idwm;
      const float* bp = g_bias + (h << 12) + jm + 8 * mi;
#pragma unroll
      for (int rr = 0; rr < 4; ++rr) {
        P[rr][mi] = bp[rowN[rr] << 6] + ((idm == idn[rr]) ? 0.0f : -100.0f);
      }
    }
  }
  __syncthreads();

  // ---- 1/||k_m|| (wave 0 only; wave-uniform branch, no divergence) ----
  if (t < 64) {
    const float4* kp = (const float4*)(sk + t * HD);
    float ss = 0.0f;
#pragma unroll
    for (int i = 0; i < 6; ++i) {
      const float4 k4 = kp[i];
      ss = fmaf(k4.x, k4.x, fmaf(k4.y, k4.y, fmaf(k4.z, k4.z, fmaf(k4.w, k4.w, ss))));
    }
    sik[t] = 1.0f / fmaxf(sqrtf(ss), 1e-12f);
  }

  // ---- normalize q by logit_scale/||q|| (q already in registers) ----
  const float scale = expf(fminf(logit_scale[h], 4.6051701860f));  // ln(100)
#pragma unroll
  for (int rr = 0; rr < 4; ++rr) {
    float ss = 0.0f;
#pragma unroll
    for (int d = 0; d < HD; ++d) ss = fmaf(q[rr][d], q[rr][d], ss);
    const float sc = scale / fmaxf(sqrtf(ss), 1e-12f);
#pragma unroll
    for (int d = 0; d < HD; ++d) q[rr][d] *= sc;
  }
  __syncthreads();  // sik visible (k/v staged earlier)

  // ---- hoist the 8 sik scalar LDS reads off the QK^T critical path ----
  float ikv[8];
#pragma unroll
  for (int mi = 0; mi < 8; ++mi) ikv[mi] = sik[jm + 8 * mi];

  // ---- QK^T * scale + (preloaded bias+mask) -> exp, running row sums ----
  // no max-subtraction needed: s <= 10*1 + 16 = 26, exp(26) ~ 2e11 (f32-safe)
  float sum[4] = {0.f, 0.f, 0.f, 0.f};
#pragma unroll
  for (int mi = 0; mi < 8; ++mi) {
    const int m = jm + 8 * mi;                          // r2 = mi
    float kv[HD];
    {
      const float4* kp = (const float4*)(sk + m * HD);
#pragma unroll
      for (int i = 0; i < 6; ++i) {
        const float4 v4 = kp[i];
        kv[4 * i] = v4.x; kv[4 * i + 1] = v4.y; kv[4 * i + 2] = v4.z; kv[4 * i + 3] = v4.w;
      }
    }
    const float ik = ikv[mi];
#pragma unroll
    for (int rr = 0; rr < 4; ++rr) {
      float s = 0.0f;
#pragma unroll
      for (int d = 0; d < HD; ++d) s = fmaf(q[rr][d], kv[d], s);
      const float e = __expf(fmaf(s, ik, P[rr][mi]));
      P[rr][mi] = e;
      sum[rr] += e;
    }
  }

  // ---- softmax denominators (8-lane DPP reduce) ----
  float rs[4];
#pragma unroll
  for (int rr = 0; rr < 4; ++rr) rs[rr] = 1.0f / red8(sum[rr]);

  // ---- PV ----
  float acc[4][HD];
#pragma unroll
  for (int rr = 0; rr < 4; ++rr)
#pragma unroll
    for (int d = 0; d < HD; ++d) acc[rr][d] = 0.0f;

#pragma unroll
  for (int mi = 0; mi < 8; ++mi) {
    const int m = jm + 8 * mi;
    float vv[HD];
    const float4* vp = (const float4*)(sv + m * HD);
#pragma unroll
    for (int i = 0; i < 6; ++i) {
      const float4 v4 = vp[i];
      vv[4 * i] = v4.x; vv[4 * i + 1] = v4.y; vv[4 * i + 2] = v4.z; vv[4 * i + 3] = v4.w;
    }
#pragma unroll
    for (int rr = 0; rr < 4; ++rr) {
      const float p = P[rr][mi];
#pragma unroll
      for (int d = 0; d < HD; ++d) acc[rr][d] = fmaf(p, vv[d], acc[rr][d]);
    }
  }

  // ---- scale + cross-lane reduce (all 8 lanes end with full sums) ----
#pragma unroll
  for (int rr = 0; rr < 4; ++rr)
#pragma unroll
    for (int d = 0; d < HD; ++d) acc[rr][d] = red8(acc[rr][d] * rs[rr]);

  // ---- store: lane jm -> (row jm&3, 12-float half jm>>2); cndmask select
  // (no runtime register-array indexing -> no scratch, rule #20) ----
  float o[12];
  const int s0 = jm & 1, s1 = jm & 2, s2 = jm & 4;
#pragma unroll
  for (int k = 0; k < 12; ++k) {
    const float lo = s1 ? (s0 ? acc[3][k] : acc[2][k])
                        : (s0 ? acc[1][k] : acc[0][k]);
    const float hi = s1 ? (s0 ? acc[3][12 + k] : acc[2][12 + k])
                        : (s0 ? acc[1][12 + k] : acc[0][12 + k]);
    o[k] = s2 ? hi : lo;
  }
  {
    const int n = wv * 32 + nr * 4 + (jm & 3);
    const int r = n >> 3, c = n & 7;
    const int hg = (wh * 8 + r + 4) & 255;
    const int wg = (ww * 8 + c + 4) & 255;
    float* op = out + (size_t)((b * 256 + hg) * 256 + wg) * 144
              + 24 * h + 12 * ((jm >> 2) & 1);
    *(float4*)(op + 0) = make_float4(o[0], o[1], o[2],  o[3]);
    *(float4*)(op + 4) = make_float4(o[4], o[5], o[6],  o[7]);
    *(float4*)(op + 8) = make_float4(o[8], o[9], o[10], o[11]);
  }
}

// ---------------- launcher --------------------------------------------------
extern "C" void kernel_launch(void* const* d_in, const int* in_sizes, int n_in,
                              void* d_out, int out_size, void* d_ws, size_t ws_size,
                              hipStream_t stream) {
  (void)n_in; (void)out_size; (void)d_ws; (void)ws_size;
  const float* qkv = (const float*)d_in[0];
  const float* ls  = (const float*)d_in[1];
  const float* w1  = (const float*)d_in[2];
  const float* b1  = (const float*)d_in[3];
  const float* w2  = (const float*)d_in[4];
  // d_in[5], d_in[6] are H, W (256, 256) — compile-time constants here
  float* outp = (float*)d_out;
  const int B = in_sizes[0] / (256 * 256 * 432);

  hipLaunchKernelGGL(cpb_mlp_kernel, dim3(225), dim3(512), 0, stream,
                     w1, b1, w2);
  hipLaunchKernelGGL(cpb_gather_kernel, dim3(96), dim3(256), 0, stream);
  hipLaunchKernelGGL(win_attn_kernel, dim3(NH, NWX * NWX, B), dim3(128), 0,
                     stream, qkv, ls, outp);
}